// Round 3
// baseline (1643.981 us; speedup 1.0000x reference)
//
#include <hip/hip_runtime.h>
#include <hip/hip_bf16.h>
#include <cmath>

typedef __bf16 bf16;
typedef bf16 bf16x8 __attribute__((ext_vector_type(8)));
typedef bf16 bf16x4 __attribute__((ext_vector_type(4)));
typedef float f32x4 __attribute__((ext_vector_type(4)));

#define GLD_LDS16(g, l)                                                        \
    __builtin_amdgcn_global_load_lds(                                          \
        (__attribute__((address_space(1))) void*)(g),                          \
        (__attribute__((address_space(3))) void*)(l), 16, 0, 0)

// ---------------------------------------------------------------- converts
__global__ __launch_bounds__(256) void convert_f32_bf16_k(
    const float* __restrict__ in, bf16* __restrict__ out, long n4)
{
    long i = (long)blockIdx.x * 256 + threadIdx.x;
    if (i < n4) {
        float4 v = reinterpret_cast<const float4*>(in)[i];
        bf16x4 o = { (bf16)v.x, (bf16)v.y, (bf16)v.z, (bf16)v.w };
        reinterpret_cast<bf16x4*>(out)[i] = o;
    }
}

// in [R,C] f32 -> out [C,R] bf16 (scaled)
__global__ __launch_bounds__(256) void transpose_f32_bf16_k(
    const float* __restrict__ in, bf16* __restrict__ out, int R, int C, float scale)
{
    __shared__ float tile[32][33];
    const int c = threadIdx.x & 31, r0 = threadIdx.x >> 5;
    const int ib = blockIdx.y * 32, ob = blockIdx.x * 32;
#pragma unroll
    for (int rr = 0; rr < 32; rr += 8)
        tile[r0 + rr][c] = in[(long)(ib + r0 + rr) * C + ob + c];
    __syncthreads();
#pragma unroll
    for (int rr = 0; rr < 32; rr += 8)
        out[(long)(ob + r0 + rr) * R + ib + c] = (bf16)(tile[c][r0 + rr] * scale);
}

// per-z: in [R,C] bf16 -> out [C,R] bf16
__global__ __launch_bounds__(256) void transpose_bf16_k(
    const bf16* __restrict__ in, bf16* __restrict__ out, int R, int C, long inZ, long outZ)
{
    __shared__ bf16 tile[32][33];
    const long zi = (long)blockIdx.z * inZ, zo = (long)blockIdx.z * outZ;
    const int c = threadIdx.x & 31, r0 = threadIdx.x >> 5;
    const int ib = blockIdx.y * 32, ob = blockIdx.x * 32;
#pragma unroll
    for (int rr = 0; rr < 32; rr += 8)
        tile[r0 + rr][c] = in[zi + (long)(ib + r0 + rr) * C + ob + c];
    __syncthreads();
#pragma unroll
    for (int rr = 0; rr < 32; rr += 8)
        out[zo + (long)(ob + r0 + rr) * R + ib + c] = tile[c][r0 + rr];
}

// ---------------------------------------------------------------- GEMM (BT form)
// C[M,N] = A[M,K] * Bt[N,K]^T, bf16 in, fp32 accum. 128x128 tile, BK=64,
// 4 waves, 16x16x32 MFMA, global_load_lds width-16 staging (m97 structure).
// Output addr = z*cZ + (m/Mb)*S1 + (m%Mb)*rowStride + (n/Nb)*S2 + (n%Nb).
// OUT_MODE: 1 = bf16 store
//           2 = f32 store + bias[n]
//           3 = bf16(exp(acc)) store + atomicAdd row sums into rowsum[z*rsZ+row]
//           4 = bf16(acc * (1/rowsum[z*rsZ+row])) store
template<int OUT_MODE>
__global__ __launch_bounds__(256, 2) void gemm_bt_k(
    const bf16* __restrict__ A, const bf16* __restrict__ B, void* __restrict__ Cv,
    int K, long aZ, long bZ, long cZ,
    int Mb, long S1, int Nb, long S2, long rowStride,
    const float* __restrict__ bias, float* __restrict__ rowsum, long rsZ)
{
    __shared__ __align__(16) bf16 lA[128 * 64];
    __shared__ __align__(16) bf16 lB[128 * 64];
    const int tid = threadIdx.x;
    const int z = blockIdx.z;
    const int mBase = blockIdx.y * 128;
    const int nBase = blockIdx.x * 128;
    A += (long)z * aZ;
    B += (long)z * bZ;
    const long cbase = (long)z * cZ
        + (long)(mBase / Mb) * S1 + (long)(mBase % Mb) * rowStride
        + (long)(nBase / Nb) * S2 + (nBase % Nb);
    const int w = tid >> 6, l = tid & 63;
    const int wr = (w >> 1) * 64, wc = (w & 1) * 64;

    f32x4 acc[4][4];
#pragma unroll
    for (int i = 0; i < 4; i++)
#pragma unroll
        for (int j = 0; j < 4; j++)
            acc[i][j] = f32x4{0.f, 0.f, 0.f, 0.f};

    // staging: each lane loads 16B (8 bf16); 4 issues cover a 128x64 tile
    const int srow = tid >> 3;
    const int scol = (tid & 7) * 8;
    const bf16* ga = A + (long)(mBase + srow) * K + scol;
    const bf16* gb = B + (long)(nBase + srow) * K + scol;
    char* lAb = reinterpret_cast<char*>(lA);
    char* lBb = reinterpret_cast<char*>(lB);
    const int ldsW = (tid & 192) * 16;  // wave-uniform LDS base (bytes)

    const int aOff = (wr + (l & 15)) * 64 + (l >> 4) * 8;  // elements
    const int bOff = (wc + (l & 15)) * 64 + (l >> 4) * 8;

    for (int k0 = 0; k0 < K; k0 += 64) {
#pragma unroll
        for (int i = 0; i < 4; i++) {
            GLD_LDS16(ga + (long)i * 32 * K + k0, lAb + i * 4096 + ldsW);
            GLD_LDS16(gb + (long)i * 32 * K + k0, lBb + i * 4096 + ldsW);
        }
        __syncthreads();
#pragma unroll
        for (int kk = 0; kk < 64; kk += 32) {
            bf16x8 af[4], bfr[4];
#pragma unroll
            for (int i = 0; i < 4; i++)
                af[i] = *reinterpret_cast<const bf16x8*>(lAb + (aOff + i * 1024 + kk) * 2);
#pragma unroll
            for (int j = 0; j < 4; j++)
                bfr[j] = *reinterpret_cast<const bf16x8*>(lBb + (bOff + j * 1024 + kk) * 2);
#pragma unroll
            for (int i = 0; i < 4; i++)
#pragma unroll
                for (int j = 0; j < 4; j++)
                    acc[i][j] = __builtin_amdgcn_mfma_f32_16x16x32_bf16(af[i], bfr[j], acc[i][j], 0, 0, 0);
        }
        __syncthreads();
    }

    const int lcol = l & 15;
    const int lrow = (l >> 4) * 4;

    if (OUT_MODE == 3) {
        // exp in place
#pragma unroll
        for (int i = 0; i < 4; i++)
#pragma unroll
            for (int j = 0; j < 4; j++)
#pragma unroll
                for (int r = 0; r < 4; r++)
                    acc[i][j][r] = __expf(acc[i][j][r]);
        // per-row partial sums over this block's 128 cols (wave covers 64)
#pragma unroll
        for (int i = 0; i < 4; i++)
#pragma unroll
            for (int r = 0; r < 4; r++) {
                float p = acc[i][0][r] + acc[i][1][r] + acc[i][2][r] + acc[i][3][r];
                p += __shfl_xor(p, 1);
                p += __shfl_xor(p, 2);
                p += __shfl_xor(p, 4);
                p += __shfl_xor(p, 8);
                if ((l & 15) == 0)
                    atomicAdd(&rowsum[(long)z * rsZ + mBase + wr + i * 16 + lrow + r], p);
            }
        bf16* C = reinterpret_cast<bf16*>(Cv);
#pragma unroll
        for (int i = 0; i < 4; i++)
#pragma unroll
            for (int j = 0; j < 4; j++)
#pragma unroll
                for (int r = 0; r < 4; r++)
                    C[cbase + (long)(wr + i * 16 + lrow + r) * rowStride + wc + j * 16 + lcol]
                        = (bf16)acc[i][j][r];
    } else if (OUT_MODE == 4) {
        bf16* C = reinterpret_cast<bf16*>(Cv);
#pragma unroll
        for (int i = 0; i < 4; i++)
#pragma unroll
            for (int r = 0; r < 4; r++) {
                const float inv = 1.0f / rowsum[(long)z * rsZ + mBase + wr + i * 16 + lrow + r];
#pragma unroll
                for (int j = 0; j < 4; j++)
                    C[cbase + (long)(wr + i * 16 + lrow + r) * rowStride + wc + j * 16 + lcol]
                        = (bf16)(acc[i][j][r] * inv);
            }
    } else if (OUT_MODE == 1) {
        bf16* C = reinterpret_cast<bf16*>(Cv);
#pragma unroll
        for (int i = 0; i < 4; i++)
#pragma unroll
            for (int j = 0; j < 4; j++)
#pragma unroll
                for (int r = 0; r < 4; r++)
                    C[cbase + (long)(wr + i * 16 + lrow + r) * rowStride + wc + j * 16 + lcol]
                        = (bf16)acc[i][j][r];
    } else {  // 2: f32 + bias
        float* C = reinterpret_cast<float*>(Cv);
        float bv[4];
#pragma unroll
        for (int j = 0; j < 4; j++)
            bv[j] = bias[nBase + wc + j * 16 + lcol];
#pragma unroll
        for (int i = 0; i < 4; i++)
#pragma unroll
            for (int j = 0; j < 4; j++)
#pragma unroll
                for (int r = 0; r < 4; r++)
                    C[cbase + (long)(wr + i * 16 + lrow + r) * rowStride + wc + j * 16 + lcol]
                        = acc[i][j][r] + bv[j];
    }
}

// ---------------------------------------------------------------- launch
extern "C" void kernel_launch(void* const* d_in, const int* in_sizes, int n_in,
                              void* d_out, int out_size, void* d_ws, size_t ws_size,
                              hipStream_t stream)
{
    const float* x  = (const float*)d_in[0];
    const float* Wq = (const float*)d_in[1];
    const float* Wk = (const float*)d_in[2];
    const float* Wv = (const float*)d_in[3];
    const float* Wu = (const float*)d_in[4];
    const float* bu = (const float*)d_in[5];
    float* out = (float*)d_out;

    constexpr int Bb = 4, T = 2048, E = 768, H = 8, HE = 6144, BT = 8192;
    constexpr int QKVN = 3 * HE;  // 18432
    const int BIG = 1 << 30;

    char* ws = (char*)d_ws;
    size_t off = 0;
    auto alloc = [&](size_t bytes) { size_t o = off; off += (bytes + 255) & ~(size_t)255; return o; };
    bf16* Wqkvt  = (bf16*)(ws + alloc((size_t)QKVN * E * 2));  // [18432,768]: rows 0-6143 Wq^T*qs, 6144-12287 Wk^T*qs, 12288+ Wv^T
    bf16* Wut    = (bf16*)(ws + alloc((size_t)E * HE * 2));    // [768,6144]
    bf16* xb     = (bf16*)(ws + alloc((size_t)BT * E * 2));    // [8192,768]
    bf16* QKVb   = (bf16*)(ws + alloc((size_t)24 * T * E * 2));// per-batch [slot][2048][768], slot=h / 8+h / 16+h
    bf16* Vt     = (bf16*)(ws + alloc((size_t)H * E * T * 2)); // per-batch [h][768][2048]
    bf16* Ob     = (bf16*)(ws + alloc((size_t)T * HE * 2));    // per-batch [2048][6144]
    float* rowsum= (float*)(ws + alloc((size_t)H * T * 4));    // per-batch [h][2048]
    size_t ebOff = off;
    int hc = 8;  // heads per attention chunk; shrink to fit ws_size
    while (hc > 1 && ebOff + (size_t)hc * T * T * 2 > ws_size) hc >>= 1;
    bf16* Eb = (bf16*)(ws + ebOff);                            // [hc][2048][2048] unnormalized exp(S)

    const float qs = 1.0f / powf((float)E, 0.25f);  // fold score scaling into Wq AND Wk

    convert_f32_bf16_k<<<dim3((BT * E / 4) / 256), dim3(256), 0, stream>>>(x, xb, (long)BT * E / 4);
    transpose_f32_bf16_k<<<dim3(HE / 32, E / 32), dim3(256), 0, stream>>>(Wq, Wqkvt, E, HE, qs);
    transpose_f32_bf16_k<<<dim3(HE / 32, E / 32), dim3(256), 0, stream>>>(Wk, Wqkvt + (size_t)HE * E, E, HE, qs);
    transpose_f32_bf16_k<<<dim3(HE / 32, E / 32), dim3(256), 0, stream>>>(Wv, Wqkvt + (size_t)2 * HE * E, E, HE, 1.0f);
    transpose_f32_bf16_k<<<dim3(E / 32, HE / 32), dim3(256), 0, stream>>>(Wu, Wut, HE, E, 1.0f);

    for (int b = 0; b < Bb; b++) {
        // fused QKV projection: [2048,768] x [18432,768]^T -> QKVb slots
        gemm_bt_k<1><<<dim3(QKVN / 128, T / 128, 1), dim3(256), 0, stream>>>(
            xb + (long)b * T * E, Wqkvt, QKVb, E, 0, 0, 0,
            BIG, 0, E, (long)T * E, E, nullptr, nullptr, 0);

        // V [h,t,e] -> Vt [h,e,t]
        transpose_bf16_k<<<dim3(E / 32, T / 32, H), dim3(256), 0, stream>>>(
            QKVb + (size_t)16 * T * E, Vt, T, E, (long)T * E, (long)E * T);

        hipMemsetAsync(rowsum, 0, (size_t)H * T * 4, stream);

        for (int h0 = 0; h0 < H; h0 += hc) {
            // E[h][t][s] = exp(q.k); rowsum[h][t] += partials
            gemm_bt_k<3><<<dim3(T / 128, T / 128, hc), dim3(256), 0, stream>>>(
                QKVb + (long)h0 * T * E, QKVb + (long)(8 + h0) * T * E, Eb,
                E, (long)T * E, (long)T * E, (long)T * T,
                BIG, 0, BIG, 0, T, nullptr, rowsum + (long)h0 * T, T);
            // O[t][(h0+z)*768+e] = (E @ V) / rowsum
            gemm_bt_k<4><<<dim3(E / 128, T / 128, hc), dim3(256), 0, stream>>>(
                Eb, Vt + (long)h0 * E * T, Ob + (long)h0 * E,
                T, (long)T * T, (long)E * T, (long)E,
                BIG, 0, BIG, 0, HE, nullptr, rowsum + (long)h0 * T, T);
        }

        // out[b*2048+t][e] = O @ Wu + bu
        gemm_bt_k<2><<<dim3(E / 128, T / 128, 1), dim3(256), 0, stream>>>(
            Ob, Wut, out + (long)b * T * E, HE, 0, 0, 0,
            BIG, 0, BIG, 0, E, bu, nullptr, 0);
    }
}

// Round 5
// 1346.983 us; speedup vs baseline: 1.2205x; 1.2205x over previous
//
#include <hip/hip_runtime.h>
#include <hip/hip_bf16.h>
#include <cmath>

typedef __bf16 bf16;
typedef bf16 bf16x8 __attribute__((ext_vector_type(8)));
typedef bf16 bf16x4 __attribute__((ext_vector_type(4)));
typedef float f32x4 __attribute__((ext_vector_type(4)));

#define GLD_LDS16(g, l)                                                        \
    __builtin_amdgcn_global_load_lds(                                          \
        (__attribute__((address_space(1))) void*)(g),                          \
        (__attribute__((address_space(3))) void*)(l), 16, 0, 0)

// ---------------------------------------------------------------- converts
__global__ __launch_bounds__(256) void convert_f32_bf16_k(
    const float* __restrict__ in, bf16* __restrict__ out, long n4)
{
    long i = (long)blockIdx.x * 256 + threadIdx.x;
    if (i < n4) {
        float4 v = reinterpret_cast<const float4*>(in)[i];
        bf16x4 o = { (bf16)v.x, (bf16)v.y, (bf16)v.z, (bf16)v.w };
        reinterpret_cast<bf16x4*>(out)[i] = o;
    }
}

// in [R,C] f32 -> out [C,R] bf16 (scaled)
__global__ __launch_bounds__(256) void transpose_f32_bf16_k(
    const float* __restrict__ in, bf16* __restrict__ out, int R, int C, float scale)
{
    __shared__ float tile[32][33];
    const int c = threadIdx.x & 31, r0 = threadIdx.x >> 5;
    const int ib = blockIdx.y * 32, ob = blockIdx.x * 32;
#pragma unroll
    for (int rr = 0; rr < 32; rr += 8)
        tile[r0 + rr][c] = in[(long)(ib + r0 + rr) * C + ob + c];
    __syncthreads();
#pragma unroll
    for (int rr = 0; rr < 32; rr += 8)
        out[(long)(ob + r0 + rr) * R + ib + c] = (bf16)(tile[c][r0 + rr] * scale);
}

// per-z: in [R,C] bf16 -> out [C,R] bf16
__global__ __launch_bounds__(256) void transpose_bf16_k(
    const bf16* __restrict__ in, bf16* __restrict__ out, int R, int C, long inZ, long outZ)
{
    __shared__ bf16 tile[32][33];
    const long zi = (long)blockIdx.z * inZ, zo = (long)blockIdx.z * outZ;
    const int c = threadIdx.x & 31, r0 = threadIdx.x >> 5;
    const int ib = blockIdx.y * 32, ob = blockIdx.x * 32;
#pragma unroll
    for (int rr = 0; rr < 32; rr += 8)
        tile[r0 + rr][c] = in[zi + (long)(ib + r0 + rr) * C + ob + c];
    __syncthreads();
#pragma unroll
    for (int rr = 0; rr < 32; rr += 8)
        out[zo + (long)(ob + r0 + rr) * R + ib + c] = tile[c][r0 + rr];
}

// ---------------------------------------------------------------- reduce
// out[i] = sum_z part[z*chunkElems + i] + bias[col(i)]; f32x4-vectorized,
// row width 768 f32 = 192 f32x4.
__global__ __launch_bounds__(256) void reduce_bias_k(
    const float* __restrict__ part, const float* __restrict__ bias,
    float* __restrict__ out, int nChunks, long chunkElems, long n4)
{
    long i = (long)blockIdx.x * 256 + threadIdx.x;
    if (i >= n4) return;
    float4 s = reinterpret_cast<const float4*>(part)[i];
    for (int z = 1; z < nChunks; z++) {
        float4 v = reinterpret_cast<const float4*>(part + (long)z * chunkElems)[i];
        s.x += v.x; s.y += v.y; s.z += v.z; s.w += v.w;
    }
    const float4 bv = *reinterpret_cast<const float4*>(bias + ((i % 192) << 2));
    s.x += bv.x; s.y += bv.y; s.z += bv.z; s.w += bv.w;
    reinterpret_cast<float4*>(out)[i] = s;
}

// ---------------------------------------------------------------- GEMM (BT form)
// C[M,N] = A[M,K] * Bt[N,K]^T, bf16 in, fp32 accum. 128x128 tile, BK=64,
// 4 waves, 16x16x32 MFMA, global_load_lds width-16 staging (m97 structure).
// lda/ldb are A/B row strides (elements), decoupled from loop bound K for split-K.
// Output addr = z*cZ + (m/Mb)*S1 + (m%Mb)*rowStride + (n/Nb)*S2 + (n%Nb).
// OUT_MODE: 1 = bf16 store
//           2 = f32 store + bias[n]
//           3 = bf16(exp(acc)) store + atomicAdd row sums into rowsum[z*rsZ+row]
//           4 = bf16(acc * (1/rowsum[z*rsZ+row])) store
//           5 = f32 store (split-K partials)
template<int OUT_MODE>
__global__ __launch_bounds__(256, 2) void gemm_bt_k(
    const bf16* __restrict__ A, const bf16* __restrict__ B, void* __restrict__ Cv,
    int K, int lda, int ldb, long aZ, long bZ, long cZ,
    int Mb, long S1, int Nb, long S2, long rowStride,
    const float* __restrict__ bias, float* __restrict__ rowsum, long rsZ)
{
    __shared__ __align__(16) bf16 lA[128 * 64];
    __shared__ __align__(16) bf16 lB[128 * 64];
    const int tid = threadIdx.x;
    const int z = blockIdx.z;
    const int mBase = blockIdx.y * 128;
    const int nBase = blockIdx.x * 128;
    A += (long)z * aZ;
    B += (long)z * bZ;
    const long cbase = (long)z * cZ
        + (long)(mBase / Mb) * S1 + (long)(mBase % Mb) * rowStride
        + (long)(nBase / Nb) * S2 + (nBase % Nb);
    const int w = tid >> 6, l = tid & 63;
    const int wr = (w >> 1) * 64, wc = (w & 1) * 64;

    f32x4 acc[4][4];
#pragma unroll
    for (int i = 0; i < 4; i++)
#pragma unroll
        for (int j = 0; j < 4; j++)
            acc[i][j] = f32x4{0.f, 0.f, 0.f, 0.f};

    // staging: each lane loads 16B (8 bf16); 4 issues cover a 128x64 tile
    const int srow = tid >> 3;
    const int scol = (tid & 7) * 8;
    const bf16* ga = A + (long)(mBase + srow) * lda + scol;
    const bf16* gb = B + (long)(nBase + srow) * ldb + scol;
    char* lAb = reinterpret_cast<char*>(lA);
    char* lBb = reinterpret_cast<char*>(lB);
    const int ldsW = (tid & 192) * 16;  // wave-uniform LDS base (bytes)

    const int aOff = (wr + (l & 15)) * 64 + (l >> 4) * 8;  // elements
    const int bOff = (wc + (l & 15)) * 64 + (l >> 4) * 8;

    for (int k0 = 0; k0 < K; k0 += 64) {
#pragma unroll
        for (int i = 0; i < 4; i++) {
            GLD_LDS16(ga + (long)i * 32 * lda + k0, lAb + i * 4096 + ldsW);
            GLD_LDS16(gb + (long)i * 32 * ldb + k0, lBb + i * 4096 + ldsW);
        }
        __syncthreads();
#pragma unroll
        for (int kk = 0; kk < 64; kk += 32) {
            bf16x8 af[4], bfr[4];
#pragma unroll
            for (int i = 0; i < 4; i++)
                af[i] = *reinterpret_cast<const bf16x8*>(lAb + (aOff + i * 1024 + kk) * 2);
#pragma unroll
            for (int j = 0; j < 4; j++)
                bfr[j] = *reinterpret_cast<const bf16x8*>(lBb + (bOff + j * 1024 + kk) * 2);
#pragma unroll
            for (int i = 0; i < 4; i++)
#pragma unroll
                for (int j = 0; j < 4; j++)
                    acc[i][j] = __builtin_amdgcn_mfma_f32_16x16x32_bf16(af[i], bfr[j], acc[i][j], 0, 0, 0);
        }
        __syncthreads();
    }

    const int lcol = l & 15;
    const int lrow = (l >> 4) * 4;

    if (OUT_MODE == 3) {
        // exp in place
#pragma unroll
        for (int i = 0; i < 4; i++)
#pragma unroll
            for (int j = 0; j < 4; j++)
#pragma unroll
                for (int r = 0; r < 4; r++)
                    acc[i][j][r] = __expf(acc[i][j][r]);
        // per-row partial sums over this block's 128 cols (wave covers 64)
#pragma unroll
        for (int i = 0; i < 4; i++)
#pragma unroll
            for (int r = 0; r < 4; r++) {
                float p = acc[i][0][r] + acc[i][1][r] + acc[i][2][r] + acc[i][3][r];
                p += __shfl_xor(p, 1);
                p += __shfl_xor(p, 2);
                p += __shfl_xor(p, 4);
                p += __shfl_xor(p, 8);
                if ((l & 15) == 0)
                    atomicAdd(&rowsum[(long)z * rsZ + mBase + wr + i * 16 + lrow + r], p);
            }
        bf16* C = reinterpret_cast<bf16*>(Cv);
#pragma unroll
        for (int i = 0; i < 4; i++)
#pragma unroll
            for (int j = 0; j < 4; j++)
#pragma unroll
                for (int r = 0; r < 4; r++)
                    C[cbase + (long)(wr + i * 16 + lrow + r) * rowStride + wc + j * 16 + lcol]
                        = (bf16)acc[i][j][r];
    } else if (OUT_MODE == 4) {
        bf16* C = reinterpret_cast<bf16*>(Cv);
#pragma unroll
        for (int i = 0; i < 4; i++)
#pragma unroll
            for (int r = 0; r < 4; r++) {
                const float inv = 1.0f / rowsum[(long)z * rsZ + mBase + wr + i * 16 + lrow + r];
#pragma unroll
                for (int j = 0; j < 4; j++)
                    C[cbase + (long)(wr + i * 16 + lrow + r) * rowStride + wc + j * 16 + lcol]
                        = (bf16)(acc[i][j][r] * inv);
            }
    } else if (OUT_MODE == 1) {
        bf16* C = reinterpret_cast<bf16*>(Cv);
#pragma unroll
        for (int i = 0; i < 4; i++)
#pragma unroll
            for (int j = 0; j < 4; j++)
#pragma unroll
                for (int r = 0; r < 4; r++)
                    C[cbase + (long)(wr + i * 16 + lrow + r) * rowStride + wc + j * 16 + lcol]
                        = (bf16)acc[i][j][r];
    } else {  // 2: f32 + bias, 5: f32 partial
        float* C = reinterpret_cast<float*>(Cv);
        float bv[4] = {0.f, 0.f, 0.f, 0.f};
        if (OUT_MODE == 2) {
#pragma unroll
            for (int j = 0; j < 4; j++)
                bv[j] = bias[nBase + wc + j * 16 + lcol];
        }
#pragma unroll
        for (int i = 0; i < 4; i++)
#pragma unroll
            for (int j = 0; j < 4; j++)
#pragma unroll
                for (int r = 0; r < 4; r++)
                    C[cbase + (long)(wr + i * 16 + lrow + r) * rowStride + wc + j * 16 + lcol]
                        = acc[i][j][r] + bv[j];
    }
}

// ---------------------------------------------------------------- launch
extern "C" void kernel_launch(void* const* d_in, const int* in_sizes, int n_in,
                              void* d_out, int out_size, void* d_ws, size_t ws_size,
                              hipStream_t stream)
{
    const float* x  = (const float*)d_in[0];
    const float* Wq = (const float*)d_in[1];
    const float* Wk = (const float*)d_in[2];
    const float* Wv = (const float*)d_in[3];
    const float* Wu = (const float*)d_in[4];
    const float* bu = (const float*)d_in[5];
    float* out = (float*)d_out;

    constexpr int Bb = 4, T = 2048, E = 768, H = 8, HE = 6144, BT = 8192;
    constexpr int QKVN = 3 * HE;  // 18432
    const int BIG = 1 << 30;

    char* ws = (char*)d_ws;
    size_t off = 0;
    auto alloc = [&](size_t bytes) { size_t o = off; off += (bytes + 255) & ~(size_t)255; return o; };
    bf16* Wqkvt  = (bf16*)(ws + alloc((size_t)QKVN * E * 2));  // [18432,768]: Wq^T*qs | Wk^T*qs | Wv^T
    bf16* Wut    = (bf16*)(ws + alloc((size_t)E * HE * 2));    // [768,6144]
    bf16* xb     = (bf16*)(ws + alloc((size_t)BT * E * 2));    // [8192,768]
    bf16* QKVb   = (bf16*)(ws + alloc((size_t)24 * T * E * 2));// per-batch [slot][2048][768]
    bf16* Vt     = (bf16*)(ws + alloc((size_t)H * E * T * 2)); // per-batch [h][768][2048]
    bf16* Ob     = (bf16*)(ws + alloc((size_t)T * HE * 2));    // per-batch [2048][6144]
    float* rowsum= (float*)(ws + alloc((size_t)Bb * H * T * 4));// [b][h][2048]
    size_t ebOff = off;
    int hc = 8;  // heads per attention chunk; shrink to fit ws_size
    while (hc > 1 && ebOff + (size_t)hc * T * T * 2 > ws_size) hc >>= 1;
    bf16* Eb = (bf16*)(ws + ebOff);                            // [hc][2048][2048] unnormalized exp(S)
    // split-K partials for the final projection alias the (then-dead) Eb region
    float* Cpart = (float*)(ws + ebOff);
    size_t avail = ws_size > ebOff ? ws_size - ebOff : (size_t)hc * T * T * 2;
    int nCh = 8;  // K chunks for final projection (K=6144 -> 768 per chunk)
    while (nCh > 1 && (size_t)nCh * T * E * 4 > avail) nCh >>= 1;
    const int Kc = HE / nCh;

    const float qs = 1.0f / powf((float)E, 0.25f);  // fold score scaling into Wq AND Wk

    convert_f32_bf16_k<<<dim3((BT * E / 4) / 256), dim3(256), 0, stream>>>(x, xb, (long)BT * E / 4);
    transpose_f32_bf16_k<<<dim3(HE / 32, E / 32), dim3(256), 0, stream>>>(Wq, Wqkvt, E, HE, qs);
    transpose_f32_bf16_k<<<dim3(HE / 32, E / 32), dim3(256), 0, stream>>>(Wk, Wqkvt + (size_t)HE * E, E, HE, qs);
    transpose_f32_bf16_k<<<dim3(HE / 32, E / 32), dim3(256), 0, stream>>>(Wv, Wqkvt + (size_t)2 * HE * E, E, HE, 1.0f);
    transpose_f32_bf16_k<<<dim3(E / 32, HE / 32), dim3(256), 0, stream>>>(Wu, Wut, HE, E, 1.0f);
    hipMemsetAsync(rowsum, 0, (size_t)Bb * H * T * 4, stream);

    for (int b = 0; b < Bb; b++) {
        float* rs = rowsum + (long)b * H * T;
        // fused QKV projection: [2048,768] x [18432,768]^T -> QKVb slots
        gemm_bt_k<1><<<dim3(QKVN / 128, T / 128, 1), dim3(256), 0, stream>>>(
            xb + (long)b * T * E, Wqkvt, QKVb, E, E, E, 0, 0, 0,
            BIG, 0, E, (long)T * E, E, nullptr, nullptr, 0);

        // V [h,t,e] -> Vt [h,e,t]
        transpose_bf16_k<<<dim3(E / 32, T / 32, H), dim3(256), 0, stream>>>(
            QKVb + (size_t)16 * T * E, Vt, T, E, (long)T * E, (long)E * T);

        for (int h0 = 0; h0 < H; h0 += hc) {
            // E[h][t][s] = exp(q.k); rowsum[h][t] += partials
            gemm_bt_k<3><<<dim3(T / 128, T / 128, hc), dim3(256), 0, stream>>>(
                QKVb + (long)h0 * T * E, QKVb + (long)(8 + h0) * T * E, Eb,
                E, E, E, (long)T * E, (long)T * E, (long)T * T,
                BIG, 0, BIG, 0, T, nullptr, rs + (long)h0 * T, T);
            // O[t][(h0+z)*768+e] = (E @ V) / rowsum
            gemm_bt_k<4><<<dim3(E / 128, T / 128, hc), dim3(256), 0, stream>>>(
                Eb, Vt + (long)h0 * E * T, Ob + (long)h0 * E,
                T, T, T, (long)T * T, (long)E * T, (long)E,
                BIG, 0, BIG, 0, HE, nullptr, rs + (long)h0 * T, T);
        }

        // final projection, split-K: Cpart[z][t][e] = O[:, z*Kc:(z+1)*Kc] @ Wut-chunk
        // (Eb contents are dead after PV; Cpart aliases that region)
        gemm_bt_k<5><<<dim3(E / 128, T / 128, nCh), dim3(256), 0, stream>>>(
            Ob, Wut, Cpart, Kc, HE, HE, (long)Kc, (long)Kc, (long)T * E,
            BIG, 0, BIG, 0, E, nullptr, nullptr, 0);
        // out[b*2048+t][e] = sum_z Cpart[z] + bu
        reduce_bias_k<<<dim3((T * E / 4 + 255) / 256), dim3(256), 0, stream>>>(
            Cpart, bu, out + (long)b * T * E, nCh, (long)T * E, (long)T * E / 4);
    }
}

// Round 8
// 1195.291 us; speedup vs baseline: 1.3754x; 1.1269x over previous
//
#include <hip/hip_runtime.h>
#include <hip/hip_bf16.h>
#include <cmath>

typedef __bf16 bf16;
typedef bf16 bf16x8 __attribute__((ext_vector_type(8)));
typedef bf16 bf16x4 __attribute__((ext_vector_type(4)));
typedef float f32x4 __attribute__((ext_vector_type(4)));

#define GLD_LDS16(g, l)                                                        \
    __builtin_amdgcn_global_load_lds(                                          \
        (__attribute__((address_space(1))) void*)(g),                          \
        (__attribute__((address_space(3))) void*)(l), 16, 0, 0)

#define SBAR asm volatile("s_barrier" ::: "memory")
#define VMC4 asm volatile("s_waitcnt vmcnt(4)" ::: "memory")
#define VMC0 asm volatile("s_waitcnt vmcnt(0)" ::: "memory")

// ---------------------------------------------------------------- converts
__global__ __launch_bounds__(256) void convert_f32_bf16_k(
    const float* __restrict__ in, bf16* __restrict__ out, long n4)
{
    long i = (long)blockIdx.x * 256 + threadIdx.x;
    if (i < n4) {
        float4 v = reinterpret_cast<const float4*>(in)[i];
        bf16x4 o = { (bf16)v.x, (bf16)v.y, (bf16)v.z, (bf16)v.w };
        reinterpret_cast<bf16x4*>(out)[i] = o;
    }
}

__global__ __launch_bounds__(256) void transpose_f32_bf16_k(
    const float* __restrict__ in, bf16* __restrict__ out, int R, int C, float scale)
{
    __shared__ float tile[32][33];
    const int c = threadIdx.x & 31, r0 = threadIdx.x >> 5;
    const int ib = blockIdx.y * 32, ob = blockIdx.x * 32;
#pragma unroll
    for (int rr = 0; rr < 32; rr += 8)
        tile[r0 + rr][c] = in[(long)(ib + r0 + rr) * C + ob + c];
    __syncthreads();
#pragma unroll
    for (int rr = 0; rr < 32; rr += 8)
        out[(long)(ob + r0 + rr) * R + ib + c] = (bf16)(tile[c][r0 + rr] * scale);
}

__global__ __launch_bounds__(256) void transpose_bf16_k(
    const bf16* __restrict__ in, bf16* __restrict__ out, int R, int C, long inZ, long outZ)
{
    __shared__ bf16 tile[32][33];
    const long zi = (long)blockIdx.z * inZ, zo = (long)blockIdx.z * outZ;
    const int c = threadIdx.x & 31, r0 = threadIdx.x >> 5;
    const int ib = blockIdx.y * 32, ob = blockIdx.x * 32;
#pragma unroll
    for (int rr = 0; rr < 32; rr += 8)
        tile[r0 + rr][c] = in[zi + (long)(ib + r0 + rr) * C + ob + c];
    __syncthreads();
#pragma unroll
    for (int rr = 0; rr < 32; rr += 8)
        out[zo + (long)(ob + r0 + rr) * R + ib + c] = tile[c][r0 + rr];
}

// ---------------------------------------------------------------- reduce
__global__ __launch_bounds__(256) void reduce_bias_k(
    const float* __restrict__ part, const float* __restrict__ bias,
    float* __restrict__ out, int nChunks, long chunkElems, long n4)
{
    long i = (long)blockIdx.x * 256 + threadIdx.x;
    if (i >= n4) return;
    float4 s = reinterpret_cast<const float4*>(part)[i];
    for (int z = 1; z < nChunks; z++) {
        float4 v = reinterpret_cast<const float4*>(part + (long)z * chunkElems)[i];
        s.x += v.x; s.y += v.y; s.z += v.z; s.w += v.w;
    }
    const float4 bv = *reinterpret_cast<const float4*>(bias + ((i % 192) << 2));
    s.x += bv.x; s.y += bv.y; s.z += bv.z; s.w += bv.w;
    reinterpret_cast<float4*>(out)[i] = s;
}

// ============================================================ 256x256 8-phase GEMM
// C[M,N] = A[M,K] * Bt[N,K]^T. 8 waves (2Mx4N), BK=64 split in 2 kk-halves.
// LDS ring: 4 slots x (A 256x32 + B 256x32) = 128 KB. Counted vmcnt(4), never 0
// in steady state. XOR swizzle byte^=((byte>>7)&3)<<4 on ds_read, inverse
// pre-applied to per-lane global source (LDS dest linear, rule #21).
// OUT_MODE: 1 = bf16 store
//           3 = bf16(exp(acc)) store + atomicAdd row sums
//           4 = bf16(acc / rowsum[row]) store
template<int OUT_MODE>
__global__ __launch_bounds__(512, 2) void gemm256_k(
    const bf16* __restrict__ A, const bf16* __restrict__ B, void* __restrict__ Cv,
    int K, int lda, int ldb, long aZ, long bZ, long cZ,
    int Mb, long S1, int Nb, long S2, long rowStride,
    float* __restrict__ rowsum, long rsZ)
{
    __shared__ __align__(16) char ldsmem[131072];
    char* ldsb = ldsmem;
    const int tid = threadIdx.x;
    const int z = blockIdx.z;
    const int mBase = blockIdx.y * 256;
    const int nBase = blockIdx.x * 256;
    A += (long)z * aZ + (long)mBase * lda;
    B += (long)z * bZ + (long)nBase * ldb;
    const long cbase = (long)z * cZ
        + (long)(mBase / Mb) * S1 + (long)(mBase % Mb) * rowStride
        + (long)(nBase / Nb) * S2 + (nBase % Nb);
    const int w = tid >> 6, l = tid & 63;
    const int wm = w >> 2, wn = w & 3;   // 2 x 4 wave grid
    const int lr = l & 15, lk = l >> 4;

    f32x4 acc[8][4];
#pragma unroll
    for (int i = 0; i < 8; i++)
#pragma unroll
        for (int j = 0; j < 4; j++)
            acc[i][j] = f32x4{0.f, 0.f, 0.f, 0.f};

    // ---- staging source (pre-swizzled): chunk c -> logical chunk Lc = c^((c>>3)&3)
    const int c0 = (w << 7) + l, c1 = c0 + 64;
    const int L0 = c0 ^ ((c0 >> 3) & 3), L1 = c1 ^ ((c1 >> 3) & 3);
    const bf16* gA0 = A + (long)(L0 >> 2) * lda + (L0 & 3) * 8;
    const bf16* gA1 = A + (long)(L1 >> 2) * lda + (L1 & 3) * 8;
    const bf16* gB0 = B + (long)(L0 >> 2) * ldb + (L0 & 3) * 8;
    const bf16* gB1 = B + (long)(L1 >> 2) * ldb + (L1 & 3) * 8;
    const int dstw = w << 11;  // wave-uniform LDS dest (lane*16 added by HW)

    // ---- swizzled ds_read offsets (within a 16 KB slot part)
    int offA[8], offB[4];
#pragma unroll
    for (int mf = 0; mf < 8; mf++) {
        int row = (wm << 7) + (mf << 4) + lr;
        offA[mf] = ((row << 6) + (lk << 4)) ^ (((row >> 1) & 3) << 4);
    }
#pragma unroll
    for (int nf = 0; nf < 4; nf++) {
        int row = (wn << 6) + (nf << 4) + lr;
        offB[nf] = ((row << 6) + (lk << 4)) ^ (((row >> 1) & 3) << 4);
    }

    bf16x8 av0, av1, av2, av3, bv0, bv1, bv2, bv3;

#define STAGE_A(slot, kofs) do {                                               \
    GLD_LDS16(gA0 + (kofs), ldsb + (slot) * 32768 + dstw);                     \
    GLD_LDS16(gA1 + (kofs), ldsb + (slot) * 32768 + dstw + 1024); } while (0)
#define STAGE_B(slot, kofs) do {                                               \
    GLD_LDS16(gB0 + (kofs), ldsb + (slot) * 32768 + 16384 + dstw);             \
    GLD_LDS16(gB1 + (kofs), ldsb + (slot) * 32768 + 16384 + dstw + 1024); } while (0)
#define LD_A(s, mg) do {                                                       \
    const char* _p = ldsb + (s) * 32768;                                       \
    av0 = *(const bf16x8*)(_p + offA[(mg) * 4 + 0]);                           \
    av1 = *(const bf16x8*)(_p + offA[(mg) * 4 + 1]);                           \
    av2 = *(const bf16x8*)(_p + offA[(mg) * 4 + 2]);                           \
    av3 = *(const bf16x8*)(_p + offA[(mg) * 4 + 3]); } while (0)
#define LD_B(s) do {                                                           \
    const char* _p = ldsb + (s) * 32768 + 16384;                               \
    bv0 = *(const bf16x8*)(_p + offB[0]);                                      \
    bv1 = *(const bf16x8*)(_p + offB[1]);                                      \
    bv2 = *(const bf16x8*)(_p + offB[2]);                                      \
    bv3 = *(const bf16x8*)(_p + offB[3]); } while (0)
#define MFMA16(mg) do {                                                        \
    acc[(mg)*4+0][0] = __builtin_amdgcn_mfma_f32_16x16x32_bf16(av0, bv0, acc[(mg)*4+0][0], 0, 0, 0); \
    acc[(mg)*4+0][1] = __builtin_amdgcn_mfma_f32_16x16x32_bf16(av0, bv1, acc[(mg)*4+0][1], 0, 0, 0); \
    acc[(mg)*4+0][2] = __builtin_amdgcn_mfma_f32_16x16x32_bf16(av0, bv2, acc[(mg)*4+0][2], 0, 0, 0); \
    acc[(mg)*4+0][3] = __builtin_amdgcn_mfma_f32_16x16x32_bf16(av0, bv3, acc[(mg)*4+0][3], 0, 0, 0); \
    acc[(mg)*4+1][0] = __builtin_amdgcn_mfma_f32_16x16x32_bf16(av1, bv0, acc[(mg)*4+1][0], 0, 0, 0); \
    acc[(mg)*4+1][1] = __builtin_amdgcn_mfma_f32_16x16x32_bf16(av1, bv1, acc[(mg)*4+1][1], 0, 0, 0); \
    acc[(mg)*4+1][2] = __builtin_amdgcn_mfma_f32_16x16x32_bf16(av1, bv2, acc[(mg)*4+1][2], 0, 0, 0); \
    acc[(mg)*4+1][3] = __builtin_amdgcn_mfma_f32_16x16x32_bf16(av1, bv3, acc[(mg)*4+1][3], 0, 0, 0); \
    acc[(mg)*4+2][0] = __builtin_amdgcn_mfma_f32_16x16x32_bf16(av2, bv0, acc[(mg)*4+2][0], 0, 0, 0); \
    acc[(mg)*4+2][1] = __builtin_amdgcn_mfma_f32_16x16x32_bf16(av2, bv1, acc[(mg)*4+2][1], 0, 0, 0); \
    acc[(mg)*4+2][2] = __builtin_amdgcn_mfma_f32_16x16x32_bf16(av2, bv2, acc[(mg)*4+2][2], 0, 0, 0); \
    acc[(mg)*4+2][3] = __builtin_amdgcn_mfma_f32_16x16x32_bf16(av2, bv3, acc[(mg)*4+2][3], 0, 0, 0); \
    acc[(mg)*4+3][0] = __builtin_amdgcn_mfma_f32_16x16x32_bf16(av3, bv0, acc[(mg)*4+3][0], 0, 0, 0); \
    acc[(mg)*4+3][1] = __builtin_amdgcn_mfma_f32_16x16x32_bf16(av3, bv1, acc[(mg)*4+3][1], 0, 0, 0); \
    acc[(mg)*4+3][2] = __builtin_amdgcn_mfma_f32_16x16x32_bf16(av3, bv2, acc[(mg)*4+3][2], 0, 0, 0); \
    acc[(mg)*4+3][3] = __builtin_amdgcn_mfma_f32_16x16x32_bf16(av3, bv3, acc[(mg)*4+3][3], 0, 0, 0); } while (0)

    const int nt = K >> 6;  // K-tiles of 64 (always >= 2 here)

    // ---- prologue: stage tile 0 (kk0 -> slot0, kk1 -> slot1); wait slot0 only
    STAGE_A(0, 0); STAGE_B(0, 0);
    STAGE_A(1, 32); STAGE_B(1, 32);
    VMC4; SBAR;

    // ---- main loop: iter t reads slots (s0,s1), stages tile t+1 into (s0^2,s1^2)
    for (int t = 0; t < nt - 1; ++t) {
        const int s0 = (t & 1) << 1, s1 = s0 | 1;
        const int q0 = s0 ^ 2, q1 = s1 ^ 2;
        const int kof = (t + 1) << 6;
        // P0: mg0/kk0
        LD_A(s0, 0); LD_B(s0);
        STAGE_A(q0, kof);
        __builtin_amdgcn_sched_barrier(0);
        __builtin_amdgcn_s_setprio(1); MFMA16(0); __builtin_amdgcn_s_setprio(0);
        SBAR;
        // P1: mg1/kk0 (B frags reused)
        LD_A(s0, 1);
        STAGE_B(q0, kof);
        __builtin_amdgcn_sched_barrier(0);
        __builtin_amdgcn_s_setprio(1); MFMA16(1); __builtin_amdgcn_s_setprio(0);
        VMC4;  // waits this tile's kk1 (oldest 4 of 8 outstanding)
        SBAR;
        // P2: mg0/kk1
        LD_A(s1, 0); LD_B(s1);
        STAGE_A(q1, kof + 32);
        __builtin_amdgcn_sched_barrier(0);
        __builtin_amdgcn_s_setprio(1); MFMA16(0); __builtin_amdgcn_s_setprio(0);
        SBAR;
        // P3: mg1/kk1
        LD_A(s1, 1);
        STAGE_B(q1, kof + 32);
        __builtin_amdgcn_sched_barrier(0);
        __builtin_amdgcn_s_setprio(1); MFMA16(1); __builtin_amdgcn_s_setprio(0);
        VMC4;  // waits next tile's kk0
        SBAR;
    }
    // ---- peeled last iter (no staging)
    {
        const int s0 = ((nt - 1) & 1) << 1, s1 = s0 | 1;
        LD_A(s0, 0); LD_B(s0);
        __builtin_amdgcn_s_setprio(1); MFMA16(0); __builtin_amdgcn_s_setprio(0);
        SBAR;
        LD_A(s0, 1);
        __builtin_amdgcn_s_setprio(1); MFMA16(1); __builtin_amdgcn_s_setprio(0);
        VMC0;  // drain: kk1 (4 loads) must land
        SBAR;
        LD_A(s1, 0); LD_B(s1);
        __builtin_amdgcn_s_setprio(1); MFMA16(0); __builtin_amdgcn_s_setprio(0);
        LD_A(s1, 1);
        MFMA16(1);
    }

    // ---- epilogue
    const int rbase = (wm << 7) + (lk << 2);   // + mf*16 + r
    const int colw = (wn << 6) + lr;           // + nf*16

    if (OUT_MODE == 3) {
#pragma unroll
        for (int mf = 0; mf < 8; mf++)
#pragma unroll
            for (int nf = 0; nf < 4; nf++)
#pragma unroll
                for (int r = 0; r < 4; r++)
                    acc[mf][nf][r] = __expf(acc[mf][nf][r]);
#pragma unroll
        for (int mf = 0; mf < 8; mf++)
#pragma unroll
            for (int r = 0; r < 4; r++) {
                float p = acc[mf][0][r] + acc[mf][1][r] + acc[mf][2][r] + acc[mf][3][r];
                p += __shfl_xor(p, 1);
                p += __shfl_xor(p, 2);
                p += __shfl_xor(p, 4);
                p += __shfl_xor(p, 8);
                if (lr == 0)
                    atomicAdd(&rowsum[(long)z * rsZ + mBase + rbase + mf * 16 + r], p);
            }
        bf16* C = reinterpret_cast<bf16*>(Cv);
#pragma unroll
        for (int mf = 0; mf < 8; mf++)
#pragma unroll
            for (int nf = 0; nf < 4; nf++)
#pragma unroll
                for (int r = 0; r < 4; r++)
                    C[cbase + (long)(rbase + mf * 16 + r) * rowStride + colw + nf * 16]
                        = (bf16)acc[mf][nf][r];
    } else if (OUT_MODE == 4) {
        bf16* C = reinterpret_cast<bf16*>(Cv);
#pragma unroll
        for (int mf = 0; mf < 8; mf++)
#pragma unroll
            for (int r = 0; r < 4; r++) {
                const float inv = 1.0f / rowsum[(long)z * rsZ + mBase + rbase + mf * 16 + r];
#pragma unroll
                for (int nf = 0; nf < 4; nf++)
                    C[cbase + (long)(rbase + mf * 16 + r) * rowStride + colw + nf * 16]
                        = (bf16)(acc[mf][nf][r] * inv);
            }
    } else {  // 1: bf16 store
        bf16* C = reinterpret_cast<bf16*>(Cv);
#pragma unroll
        for (int mf = 0; mf < 8; mf++)
#pragma unroll
            for (int nf = 0; nf < 4; nf++)
#pragma unroll
                for (int r = 0; r < 4; r++)
                    C[cbase + (long)(rbase + mf * 16 + r) * rowStride + colw + nf * 16]
                        = (bf16)acc[mf][nf][r];
    }
#undef STAGE_A
#undef STAGE_B
#undef LD_A
#undef LD_B
#undef MFMA16
}

// ---------------------------------------------------------------- 128^2 GEMM (split-K final proj only)
template<int OUT_MODE>
__global__ __launch_bounds__(256, 2) void gemm_bt_k(
    const bf16* __restrict__ A, const bf16* __restrict__ B, void* __restrict__ Cv,
    int K, int lda, int ldb, long aZ, long bZ, long cZ,
    int Mb, long S1, int Nb, long S2, long rowStride,
    const float* __restrict__ bias, float* __restrict__ rowsum, long rsZ)
{
    __shared__ __align__(16) bf16 lA[128 * 64];
    __shared__ __align__(16) bf16 lB[128 * 64];
    const int tid = threadIdx.x;
    const int z = blockIdx.z;
    const int mBase = blockIdx.y * 128;
    const int nBase = blockIdx.x * 128;
    A += (long)z * aZ;
    B += (long)z * bZ;
    const long cbase = (long)z * cZ
        + (long)(mBase / Mb) * S1 + (long)(mBase % Mb) * rowStride
        + (long)(nBase / Nb) * S2 + (nBase % Nb);
    const int w = tid >> 6, l = tid & 63;
    const int wr = (w >> 1) * 64, wc = (w & 1) * 64;

    f32x4 acc[4][4];
#pragma unroll
    for (int i = 0; i < 4; i++)
#pragma unroll
        for (int j = 0; j < 4; j++)
            acc[i][j] = f32x4{0.f, 0.f, 0.f, 0.f};

    const int srow = tid >> 3;
    const int scol = (tid & 7) * 8;
    const bf16* ga = A + (long)(mBase + srow) * lda + scol;
    const bf16* gb = B + (long)(nBase + srow) * ldb + scol;
    char* lAb = reinterpret_cast<char*>(lA);
    char* lBb = reinterpret_cast<char*>(lB);
    const int ldsW = (tid & 192) * 16;

    const int aOff = (wr + (l & 15)) * 64 + (l >> 4) * 8;
    const int bOff = (wc + (l & 15)) * 64 + (l >> 4) * 8;

    for (int k0 = 0; k0 < K; k0 += 64) {
#pragma unroll
        for (int i = 0; i < 4; i++) {
            GLD_LDS16(ga + (long)i * 32 * lda + k0, lAb + i * 4096 + ldsW);
            GLD_LDS16(gb + (long)i * 32 * ldb + k0, lBb + i * 4096 + ldsW);
        }
        __syncthreads();
#pragma unroll
        for (int kk = 0; kk < 64; kk += 32) {
            bf16x8 af[4], bfr[4];
#pragma unroll
            for (int i = 0; i < 4; i++)
                af[i] = *reinterpret_cast<const bf16x8*>(lAb + (aOff + i * 1024 + kk) * 2);
#pragma unroll
            for (int j = 0; j < 4; j++)
                bfr[j] = *reinterpret_cast<const bf16x8*>(lBb + (bOff + j * 1024 + kk) * 2);
#pragma unroll
            for (int i = 0; i < 4; i++)
#pragma unroll
                for (int j = 0; j < 4; j++)
                    acc[i][j] = __builtin_amdgcn_mfma_f32_16x16x32_bf16(af[i], bfr[j], acc[i][j], 0, 0, 0);
        }
        __syncthreads();
    }

    const int lcol = l & 15;
    const int lrow = (l >> 4) * 4;
    float* C = reinterpret_cast<float*>(Cv);
#pragma unroll
    for (int i = 0; i < 4; i++)
#pragma unroll
        for (int j = 0; j < 4; j++)
#pragma unroll
            for (int r = 0; r < 4; r++)
                C[cbase + (long)(wr + i * 16 + lrow + r) * rowStride + wc + j * 16 + lcol]
                    = acc[i][j][r];
}

// ---------------------------------------------------------------- launch
extern "C" void kernel_launch(void* const* d_in, const int* in_sizes, int n_in,
                              void* d_out, int out_size, void* d_ws, size_t ws_size,
                              hipStream_t stream)
{
    const float* x  = (const float*)d_in[0];
    const float* Wq = (const float*)d_in[1];
    const float* Wk = (const float*)d_in[2];
    const float* Wv = (const float*)d_in[3];
    const float* Wu = (const float*)d_in[4];
    const float* bu = (const float*)d_in[5];
    float* out = (float*)d_out;

    constexpr int Bb = 4, T = 2048, E = 768, H = 8, HE = 6144, BT = 8192;
    constexpr int QKVN = 3 * HE;  // 18432
    const int BIG = 1 << 30;

    char* ws = (char*)d_ws;
    size_t off = 0;
    auto alloc = [&](size_t bytes) { size_t o = off; off += (bytes + 255) & ~(size_t)255; return o; };
    bf16* Wqkvt  = (bf16*)(ws + alloc((size_t)QKVN * E * 2));  // Wq^T*qs | Wk^T*qs | Wv^T
    bf16* Wut    = (bf16*)(ws + alloc((size_t)E * HE * 2));    // [768,6144]
    bf16* xb     = (bf16*)(ws + alloc((size_t)BT * E * 2));    // [8192,768]
    bf16* QKVb   = (bf16*)(ws + alloc((size_t)24 * T * E * 2));// per-batch [slot][2048][768]
    bf16* Vt     = (bf16*)(ws + alloc((size_t)H * E * T * 2)); // per-batch [h][768][2048]
    bf16* Ob     = (bf16*)(ws + alloc((size_t)T * HE * 2));    // per-batch [2048][6144]
    float* rowsum= (float*)(ws + alloc((size_t)Bb * H * T * 4));// [b][h][2048]
    size_t ebOff = off;
    int hc = 8;
    while (hc > 1 && ebOff + (size_t)hc * T * T * 2 > ws_size) hc >>= 1;
    bf16* Eb = (bf16*)(ws + ebOff);                            // [hc][2048][2048] exp(S)
    float* Cpart = (float*)(ws + ebOff);                       // aliases dead Eb
    size_t avail = ws_size > ebOff ? ws_size - ebOff : (size_t)hc * T * T * 2;
    int nCh = 8;
    while (nCh > 1 && (size_t)nCh * T * E * 4 > avail) nCh >>= 1;
    const int Kc = HE / nCh;

    const float qs = 1.0f / powf((float)E, 0.25f);

    convert_f32_bf16_k<<<dim3((BT * E / 4) / 256), dim3(256), 0, stream>>>(x, xb, (long)BT * E / 4);
    transpose_f32_bf16_k<<<dim3(HE / 32, E / 32), dim3(256), 0, stream>>>(Wq, Wqkvt, E, HE, qs);
    transpose_f32_bf16_k<<<dim3(HE / 32, E / 32), dim3(256), 0, stream>>>(Wk, Wqkvt + (size_t)HE * E, E, HE, qs);
    transpose_f32_bf16_k<<<dim3(HE / 32, E / 32), dim3(256), 0, stream>>>(Wv, Wqkvt + (size_t)2 * HE * E, E, HE, 1.0f);
    transpose_f32_bf16_k<<<dim3(E / 32, HE / 32), dim3(256), 0, stream>>>(Wu, Wut, HE, E, 1.0f);
    hipMemsetAsync(rowsum, 0, (size_t)Bb * H * T * 4, stream);

    for (int b = 0; b < Bb; b++) {
        float* rs = rowsum + (long)b * H * T;
        // fused QKV projection: [2048,768] x [18432,768]^T -> QKVb slots
        gemm256_k<1><<<dim3(QKVN / 256, T / 256, 1), dim3(512), 0, stream>>>(
            xb + (long)b * T * E, Wqkvt, QKVb, E, E, E, 0, 0, 0,
            BIG, 0, E, (long)T * E, E, nullptr, 0);

        // V [h,t,e] -> Vt [h,e,t]
        transpose_bf16_k<<<dim3(E / 32, T / 32, H), dim3(256), 0, stream>>>(
            QKVb + (size_t)16 * T * E, Vt, T, E, (long)T * E, (long)E * T);

        for (int h0 = 0; h0 < H; h0 += hc) {
            // E[h][t][s] = exp(q.k); rowsum += partials
            gemm256_k<3><<<dim3(T / 256, T / 256, hc), dim3(512), 0, stream>>>(
                QKVb + (long)h0 * T * E, QKVb + (long)(8 + h0) * T * E, Eb,
                E, E, E, (long)T * E, (long)T * E, (long)T * T,
                BIG, 0, BIG, 0, T, rs + (long)h0 * T, T);
            // O[t][(h0+z)*768+e] = (E @ V) / rowsum
            gemm256_k<4><<<dim3(E / 256, T / 256, hc), dim3(512), 0, stream>>>(
                Eb, Vt + (long)h0 * E * T, Ob + (long)h0 * E,
                T, T, T, (long)T * T, (long)E * T, (long)E,
                BIG, 0, BIG, 0, HE, rs + (long)h0 * T, T);
        }

        // final projection, split-K on the 128^2 kernel (grid width needs it)
        gemm_bt_k<5><<<dim3(E / 128, T / 128, nCh), dim3(256), 0, stream>>>(
            Ob, Wut, Cpart, Kc, HE, HE, (long)Kc, (long)Kc, (long)T * E,
            BIG, 0, BIG, 0, E, nullptr, nullptr, 0);
        reduce_bias_k<<<dim3((T * E / 4 + 255) / 256), dim3(256), 0, stream>>>(
            Cpart, bu, out + (long)b * T * E, nCh, (long)T * E, (long)T * E / 4);
    }
}